// Round 1
// baseline (2244.447 us; speedup 1.0000x reference)
//
#include <hip/hip_runtime.h>

#define NB 32
#define PP 8192
#define OPP 2048

// ======================= generic tiled transpose =======================
// out[j*R + i] = in[(i*C + j)*es + eo]
__global__ void transpose_k(const float* __restrict__ in, float* __restrict__ out,
                            int R, int C, int es, int eo) {
  __shared__ float tile[32][33];
  int jb = blockIdx.x * 32, ib = blockIdx.y * 32;
  int tx = threadIdx.x, ty = threadIdx.y;
  for (int yy = ty; yy < 32; yy += 8) {
    int i = ib + yy, j = jb + tx;
    if (i < R && j < C) tile[yy][tx] = in[((size_t)i * C + j) * (size_t)es + eo];
  }
  __syncthreads();
  for (int yy = ty; yy < 32; yy += 8) {
    int j = jb + yy, i = ib + tx;
    if (j < C && i < R) out[(size_t)j * R + i] = tile[tx][yy];
  }
}

// ======================= object-cloud mean =======================
__global__ void ocmean_k(const float* __restrict__ oc, float* __restrict__ ocm) {
  int n = blockIdx.x, t = threadIdx.x;
  __shared__ float sx[256], sy[256];
  float ax = 0.f, ay = 0.f;
  for (int p = t; p < OPP; p += 256) {
    ax += oc[((size_t)n * OPP + p) * 2 + 0];
    ay += oc[((size_t)n * OPP + p) * 2 + 1];
  }
  sx[t] = ax; sy[t] = ay;
  __syncthreads();
  for (int s = 128; s > 0; s >>= 1) {
    if (t < s) { sx[t] += sx[t + s]; sy[t] += sy[t + s]; }
    __syncthreads();
  }
  if (t == 0) {
    ocm[n * 2 + 0] = sx[0] / (float)OPP;
    ocm[n * 2 + 1] = sy[0] / (float)OPP;
  }
}

// ======================= voxel PointNet + scatter-max =======================
// block: 256 thr (4 waves). Per iter: 16 points; waves split 256 output chans.
// vox layout NHWC: [n][bi][bj][256]
__global__ __launch_bounds__(256) void pointnet_k(
    const float* __restrict__ sc, const float* __restrict__ w1, const float* __restrict__ b1,
    const float* __restrict__ w2T, const float* __restrict__ b2, float* __restrict__ vox) {
  __shared__ float hT[128 * 20];           // [k][p], padded stride 20
  __shared__ float pcx[16], pcy[16];
  __shared__ int binl[16];
  int t = threadIdx.x, lane = t & 63, w = t >> 6;
  int blk = blockIdx.x;                    // 2048 = 32 n * 64 chunks
  int n = blk >> 6, pbase0 = (blk & 63) * 128;
  int o = w * 64 + lane;                   // 0..255
  float b2o = b2[o];
  for (int it = 0; it < 8; ++it) {
    int pb = pbase0 + it * 16;
    if (t < 16) {
      float x = sc[((size_t)n * PP + pb + t) * 2 + 0];
      float y = sc[((size_t)n * PP + pb + t) * 2 + 1];
      float bif = fminf(fmaxf(ceilf((x + 0.5f) * 20.0f) - 1.0f, 0.0f), 19.0f);
      float bjf = fminf(fmaxf(ceilf((y + 0.5f) * 20.0f) - 1.0f, 0.0f), 19.0f);
      bool valid = (x > -0.5f) && (x <= 0.5f) && (y > -0.5f) && (y <= 0.5f);
      float ci = -0.5f + (bif + 0.5f) / 20.0f;
      float cj = -0.5f + (bjf + 0.5f) / 20.0f;
      pcx[t] = x - ci; pcy[t] = y - cj;
      binl[t] = valid ? ((int)bif * 20 + (int)bjf) : -1;
    }
    __syncthreads();
    {
      int c = t & 127, ph = t >> 7;
      float wx = w1[c * 2 + 0], wy = w1[c * 2 + 1], bb = b1[c];
#pragma unroll
      for (int j = 0; j < 8; ++j) {
        int p = ph * 8 + j;
        hT[c * 20 + p] = fmaxf(wx * pcx[p] + wy * pcy[p] + bb, 0.0f);
      }
    }
    __syncthreads();
    float acc[16];
#pragma unroll
    for (int j = 0; j < 16; ++j) acc[j] = 0.0f;
    for (int k = 0; k < 128; ++k) {
      float wv = w2T[k * 256 + o];
      float hv[16];
      *(float4*)&hv[0]  = *(const float4*)&hT[k * 20 + 0];
      *(float4*)&hv[4]  = *(const float4*)&hT[k * 20 + 4];
      *(float4*)&hv[8]  = *(const float4*)&hT[k * 20 + 8];
      *(float4*)&hv[12] = *(const float4*)&hT[k * 20 + 12];
#pragma unroll
      for (int j = 0; j < 16; ++j) acc[j] = fmaf(wv, hv[j], acc[j]);
    }
    size_t vbase = (size_t)n * 400 * 256 + o;
#pragma unroll
    for (int j = 0; j < 16; ++j) {
      int bn = binl[j];
      if (bn >= 0) {
        float v = fmaxf(acc[j] + b2o, 0.0f);
        atomicMax((int*)vox + vbase + (size_t)bn * 256, __float_as_int(v));
      }
    }
    __syncthreads();
  }
}

// ======================= conv1 (256->512, 3x3, pad1) + relu + maxpool2 =======================
// in: vox [n][20][20][256], out: f1 [n][10][10][512]
__global__ __launch_bounds__(256) void conv1_k(
    const float* __restrict__ vox, const float* __restrict__ wT,
    const float* __restrict__ bias, float* __restrict__ f1) {
  __shared__ float smem[12288];            // vin[4][128][24] ; reused as pout
  int b = blockIdx.x;                      // 1280 = 32 * 10 * 4
  int cg = b & 3, pr = (b >> 2) % 10, n = b / 40;
  int t = threadIdx.x, lane = t & 63, w = t >> 6;
  int rbit = w & 1, cog = w >> 1;
  int co = cg * 128 + cog * 64 + lane;     // 0..511
  float acc[20];
  float bv = bias[co];
#pragma unroll
  for (int i = 0; i < 20; ++i) acc[i] = bv;
  for (int cc = 0; cc < 2; ++cc) {
    __syncthreads();
    for (int i = t; i < 12288; i += 256) smem[i] = 0.0f;
    __syncthreads();
    for (int idx = t; idx < 4 * 20 * 128; idx += 256) {
      int ry = idx / 2560;
      int rem = idx - ry * 2560;
      int x = rem >> 7, cil = rem & 127;
      int y = pr * 2 - 1 + ry;
      if (y >= 0 && y < 20)
        smem[(ry * 128 + cil) * 24 + x + 1] =
            vox[(((size_t)n * 20 + y) * 20 + x) * 256 + cc * 128 + cil];
    }
    __syncthreads();
    for (int cil = 0; cil < 128; ++cil) {
      int ci = cc * 128 + cil;
#pragma unroll
      for (int ky = 0; ky < 3; ++ky) {
        int ry = rbit + ky;
        const float* vr = &smem[(ry * 128 + cil) * 24];
        float v[24];
#pragma unroll
        for (int q = 0; q < 6; ++q) *(float4*)&v[q * 4] = *(const float4*)&vr[q * 4];
        const float* wp = &wT[(size_t)((ci * 3 + ky) * 3) * 512 + co];
#pragma unroll
        for (int kx = 0; kx < 3; ++kx) {
          float wv = wp[(size_t)kx * 512];
#pragma unroll
          for (int ox = 0; ox < 20; ++ox) acc[ox] = fmaf(wv, v[ox + kx], acc[ox]);
        }
      }
    }
  }
  __syncthreads();
  float* pout = smem;                      // [4 waves][20][64]
#pragma unroll
  for (int ox = 0; ox < 20; ++ox) pout[(w * 20 + ox) * 64 + lane] = fmaxf(acc[ox], 0.0f);
  __syncthreads();
  {
    int l = t & 63, pg = (t >> 6) & 1, oxh = t >> 7;
    for (int ox = oxh; ox < 10; ox += 2) {
      float m0 = fmaxf(pout[((pg * 2 + 0) * 20 + 2 * ox) * 64 + l],
                       pout[((pg * 2 + 0) * 20 + 2 * ox + 1) * 64 + l]);
      float m1 = fmaxf(pout[((pg * 2 + 1) * 20 + 2 * ox) * 64 + l],
                       pout[((pg * 2 + 1) * 20 + 2 * ox + 1) * 64 + l]);
      f1[(((size_t)n * 10 + pr) * 10 + ox) * 512 + cg * 128 + pg * 64 + l] = fmaxf(m0, m1);
    }
  }
}

// ======================= conv2 (512->1024, 3x3, pad1) + relu + maxpool2 =======================
// in: f1 [n][10][10][512], out: f2 [n][5][5][1024]
__global__ __launch_bounds__(256) void conv2_k(
    const float* __restrict__ f1, const float* __restrict__ wT,
    const float* __restrict__ bias, float* __restrict__ f2) {
  __shared__ float smem[12288];            // vin[4][256][12] ; reused as pout
  int b = blockIdx.x;                      // 1280 = 32 * 5 * 8
  int cg = b & 7, pr = (b >> 3) % 5, n = b / 40;
  int t = threadIdx.x, lane = t & 63, w = t >> 6;
  int rbit = w & 1, cog = w >> 1;
  int co = cg * 128 + cog * 64 + lane;     // 0..1023
  float acc[10];
  float bv = bias[co];
#pragma unroll
  for (int i = 0; i < 10; ++i) acc[i] = bv;
  for (int cc = 0; cc < 2; ++cc) {
    __syncthreads();
    for (int i = t; i < 12288; i += 256) smem[i] = 0.0f;
    __syncthreads();
    for (int idx = t; idx < 4 * 10 * 256; idx += 256) {
      int ry = idx / 2560;
      int rem = idx - ry * 2560;
      int x = rem >> 8, cil = rem & 255;
      int y = pr * 2 - 1 + ry;
      if (y >= 0 && y < 10)
        smem[(ry * 256 + cil) * 12 + x + 1] =
            f1[(((size_t)n * 10 + y) * 10 + x) * 512 + cc * 256 + cil];
    }
    __syncthreads();
    for (int cil = 0; cil < 256; ++cil) {
      int ci = cc * 256 + cil;
#pragma unroll
      for (int ky = 0; ky < 3; ++ky) {
        int ry = rbit + ky;
        const float* vr = &smem[(ry * 256 + cil) * 12];
        float v[12];
#pragma unroll
        for (int q = 0; q < 3; ++q) *(float4*)&v[q * 4] = *(const float4*)&vr[q * 4];
        const float* wp = &wT[(size_t)((ci * 3 + ky) * 3) * 1024 + co];
#pragma unroll
        for (int kx = 0; kx < 3; ++kx) {
          float wv = wp[(size_t)kx * 1024];
#pragma unroll
          for (int ox = 0; ox < 10; ++ox) acc[ox] = fmaf(wv, v[ox + kx], acc[ox]);
        }
      }
    }
  }
  __syncthreads();
  float* pout = smem;                      // [4][10][64]
#pragma unroll
  for (int ox = 0; ox < 10; ++ox) pout[(w * 10 + ox) * 64 + lane] = fmaxf(acc[ox], 0.0f);
  __syncthreads();
  {
    int l = t & 63, pg = (t >> 6) & 1, oxh = t >> 7;
    for (int ox = oxh; ox < 5; ox += 2) {
      float m0 = fmaxf(pout[((pg * 2 + 0) * 10 + 2 * ox) * 64 + l],
                       pout[((pg * 2 + 0) * 10 + 2 * ox + 1) * 64 + l]);
      float m1 = fmaxf(pout[((pg * 2 + 1) * 10 + 2 * ox) * 64 + l],
                       pout[((pg * 2 + 1) * 10 + 2 * ox + 1) * 64 + l]);
      f2[(((size_t)n * 5 + pr) * 5 + ox) * 1024 + cg * 128 + pg * 64 + l] = fmaxf(m0, m1);
    }
  }
}

// ======================= conv transpose 2x2 s2 (1024->512) =======================
// f3[n][2ph+a][2pw+b][o] = ctb[o] + sum_i f2[n][ph][pw][i] * ctwT[a*2+b][i][o]
__global__ __launch_bounds__(256) void convt_k(
    const float* __restrict__ f2, const float* __restrict__ ctwT,
    const float* __restrict__ ctb, float* __restrict__ f3) {
  __shared__ float f2T[256 * 32];          // [i_local][px(25, pad 32)]
  int b = blockIdx.x;                      // 256 = 32 * 8
  int cog = b & 7, n = b >> 3;
  int t = threadIdx.x, lane = t & 63, w = t >> 6;
  int co = cog * 64 + lane;                // 0..511
  float acc[4][8];
#pragma unroll
  for (int a = 0; a < 4; ++a)
#pragma unroll
    for (int j = 0; j < 8; ++j) acc[a][j] = 0.0f;
  int px0 = w * 8;
  for (int ic = 0; ic < 4; ++ic) {
    __syncthreads();
    for (int i = t; i < 256 * 32; i += 256) f2T[i] = 0.0f;
    __syncthreads();
    for (int idx = t; idx < 25 * 256; idx += 256) {
      int px = idx >> 8, ii = idx & 255;
      f2T[ii * 32 + px] = f2[((size_t)n * 25 + px) * 1024 + ic * 256 + ii];
    }
    __syncthreads();
    for (int ii = 0; ii < 256; ++ii) {
      int i = ic * 256 + ii;
      float w0 = ctwT[((size_t)(0 * 1024 + i) * 512) + co];
      float w1v = ctwT[((size_t)(1 * 1024 + i) * 512) + co];
      float w2v = ctwT[((size_t)(2 * 1024 + i) * 512) + co];
      float w3v = ctwT[((size_t)(3 * 1024 + i) * 512) + co];
      float v[8];
      *(float4*)&v[0] = *(const float4*)&f2T[ii * 32 + px0];
      *(float4*)&v[4] = *(const float4*)&f2T[ii * 32 + px0 + 4];
#pragma unroll
      for (int j = 0; j < 8; ++j) {
        acc[0][j] = fmaf(w0, v[j], acc[0][j]);
        acc[1][j] = fmaf(w1v, v[j], acc[1][j]);
        acc[2][j] = fmaf(w2v, v[j], acc[2][j]);
        acc[3][j] = fmaf(w3v, v[j], acc[3][j]);
      }
    }
  }
  float bb = ctb[co];
#pragma unroll
  for (int ab = 0; ab < 4; ++ab) {
    int a = ab >> 1, bcol = ab & 1;
#pragma unroll
    for (int j = 0; j < 8; ++j) {
      int px = px0 + j;
      if (px < 25) {
        int ph = px / 5, pw = px - ph * 5;
        f3[(((size_t)n * 10 + 2 * ph + a) * 10 + 2 * pw + bcol) * 512 + co] = acc[ab][j] + bb;
      }
    }
  }
}

// ======================= object set-abstraction (fused 4 layers + max) =======================
__global__ __launch_bounds__(256) void sa_k(
    const float* __restrict__ oc, const float* __restrict__ ocm,
    const float* __restrict__ w1, const float* __restrict__ b1,
    const float* __restrict__ w2T, const float* __restrict__ b2,
    const float* __restrict__ w3T, const float* __restrict__ b3,
    const float* __restrict__ w4T, const float* __restrict__ b4,
    float* __restrict__ obj) {
  __shared__ float g1T[64 * 36];           // [k][p pad36]
  __shared__ float g2T[128 * 36];
  __shared__ float g3T[256 * 36];
  __shared__ float pcx[32], pcy[32];
  int b = blockIdx.x;                      // 2048 = 32 * 64
  int n = b >> 6, pb = (b & 63) * 32;
  int t = threadIdx.x;
  if (t < 32) {
    pcx[t] = oc[((size_t)n * OPP + pb + t) * 2 + 0] - ocm[n * 2 + 0];
    pcy[t] = oc[((size_t)n * OPP + pb + t) * 2 + 1] - ocm[n * 2 + 1];
  }
  __syncthreads();
  {                                        // stage 1: 2 -> 64
    int c = t & 63, pj = t >> 6;
    float wx = w1[c * 2], wy = w1[c * 2 + 1], bb = b1[c];
#pragma unroll
    for (int j = 0; j < 8; ++j) {
      int p = pj * 8 + j;
      g1T[c * 36 + p] = fmaxf(fmaf(wx, pcx[p], fmaf(wy, pcy[p], bb)), 0.0f);
    }
  }
  __syncthreads();
  {                                        // stage 2: 64 -> 128
    int c = t & 127, ph = t >> 7;
    float acc[16];
#pragma unroll
    for (int j = 0; j < 16; ++j) acc[j] = 0.0f;
    for (int k = 0; k < 64; ++k) {
      float wv = w2T[k * 128 + c];
      float v[16];
      const float* g = &g1T[k * 36 + ph * 16];
#pragma unroll
      for (int q = 0; q < 4; ++q) *(float4*)&v[q * 4] = *(const float4*)&g[q * 4];
#pragma unroll
      for (int j = 0; j < 16; ++j) acc[j] = fmaf(wv, v[j], acc[j]);
    }
    float bb = b2[c];
#pragma unroll
    for (int j = 0; j < 16; ++j) g2T[c * 36 + ph * 16 + j] = fmaxf(acc[j] + bb, 0.0f);
  }
  __syncthreads();
  {                                        // stage 3: 128 -> 256
    int c = t;
    float acc[32];
#pragma unroll
    for (int j = 0; j < 32; ++j) acc[j] = 0.0f;
    for (int k = 0; k < 128; ++k) {
      float wv = w3T[k * 256 + c];
      float v[32];
      const float* g = &g2T[k * 36];
#pragma unroll
      for (int q = 0; q < 8; ++q) *(float4*)&v[q * 4] = *(const float4*)&g[q * 4];
#pragma unroll
      for (int j = 0; j < 32; ++j) acc[j] = fmaf(wv, v[j], acc[j]);
    }
    float bb = b3[c];
#pragma unroll
    for (int j = 0; j < 32; ++j) g3T[c * 36 + j] = fmaxf(acc[j] + bb, 0.0f);
  }
  __syncthreads();
  {                                        // stage 4: 256 -> 512 + max over points
    int c0 = t, c1 = t + 256;
    float a0[32], a1[32];
#pragma unroll
    for (int j = 0; j < 32; ++j) { a0[j] = 0.0f; a1[j] = 0.0f; }
    for (int k = 0; k < 256; ++k) {
      float wv0 = w4T[k * 512 + c0];
      float wv1 = w4T[k * 512 + c1];
      float v[32];
      const float* g = &g3T[k * 36];
#pragma unroll
      for (int q = 0; q < 8; ++q) *(float4*)&v[q * 4] = *(const float4*)&g[q * 4];
#pragma unroll
      for (int j = 0; j < 32; ++j) {
        a0[j] = fmaf(wv0, v[j], a0[j]);
        a1[j] = fmaf(wv1, v[j], a1[j]);
      }
    }
    float m0 = a0[0], m1 = a1[0];
#pragma unroll
    for (int j = 1; j < 32; ++j) { m0 = fmaxf(m0, a0[j]); m1 = fmaxf(m1, a1[j]); }
    m0 = fmaxf(m0 + b4[c0], 0.0f);
    m1 = fmaxf(m1 + b4[c1], 0.0f);
    atomicMax((int*)obj + (size_t)n * 512 + c0, __float_as_int(m0));
    atomicMax((int*)obj + (size_t)n * 512 + c1, __float_as_int(m1));
  }
}

// ======================= classifier layer 1 (1538 -> 1024) =======================
__global__ __launch_bounds__(256) void cls1_k(
    const float* __restrict__ f1, const float* __restrict__ f3, const float* __restrict__ obj,
    const float* __restrict__ pos, const float* __restrict__ w1T, const float* __restrict__ b1,
    float* __restrict__ h1) {
  __shared__ float scT[256 * 52];          // [k][px(50, pad52)]
  int b = blockIdx.x;                      // 256 = 32 * 2 * 4
  int cg = b & 3, half = (b >> 2) & 1, n = b >> 3;
  int t = threadIdx.x, lane = t & 63, w = t >> 6;
  int co = cg * 256 + w * 64 + lane;       // 0..1023
  int p0 = half * 50;
  float od = 0.0f;                         // obj contribution (px-independent)
  for (int k = 0; k < 512; ++k)
    od = fmaf(obj[(size_t)n * 512 + k], w1T[(size_t)(1024 + k) * 1024 + co], od);
  float w1536 = w1T[(size_t)1536 * 1024 + co];
  float w1537 = w1T[(size_t)1537 * 1024 + co];
  float posx = pos[n * 2 + 0], posy = pos[n * 2 + 1];
  float bb = b1[co];
  float acc[50];
#pragma unroll
  for (int j = 0; j < 50; ++j) {
    int px = p0 + j;
    int row = px / 10, col = px - row * 10;
    float relx = posx - (-0.5f + (row + 0.5f) / 10.0f);
    float rely = posy - (-0.5f + (col + 0.5f) / 10.0f);
    acc[j] = od + bb + relx * w1536 + rely * w1537;
  }
  for (int kc = 0; kc < 1024; kc += 256) {
    __syncthreads();
    const float* src = (kc < 512) ? f1 : f3;
    int kk = (kc & 511) + t;
    for (int j = 0; j < 50; ++j)
      scT[t * 52 + j] = src[((size_t)n * 100 + p0 + j) * 512 + kk];
    __syncthreads();
    for (int k = 0; k < 256; ++k) {
      float wv = w1T[(size_t)(kc + k) * 1024 + co];
      float v[52];
      const float* g = &scT[k * 52];
#pragma unroll
      for (int q = 0; q < 13; ++q) *(float4*)&v[q * 4] = *(const float4*)&g[q * 4];
#pragma unroll
      for (int j = 0; j < 50; ++j) acc[j] = fmaf(wv, v[j], acc[j]);
    }
  }
#pragma unroll
  for (int j = 0; j < 50; ++j)
    h1[((size_t)n * 100 + p0 + j) * 1024 + co] = fmaxf(acc[j], 0.0f);
}

// ======================= classifier layer 2 (1024 -> 256) =======================
__global__ __launch_bounds__(256) void cls2_k(
    const float* __restrict__ h1, const float* __restrict__ w2T,
    const float* __restrict__ b2, float* __restrict__ h2) {
  __shared__ float scT[256 * 28];          // [k][px(25, pad28)]
  int b = blockIdx.x;                      // 128 = 32 * 4
  int q = b & 3, n = b >> 2;
  int t = threadIdx.x, lane = t & 63, w = t >> 6;
  int co = w * 64 + lane;                  // 0..255
  int p0 = q * 25;
  float acc[25];
  float bb = b2[co];
#pragma unroll
  for (int j = 0; j < 25; ++j) acc[j] = bb;
  for (int kc = 0; kc < 1024; kc += 256) {
    __syncthreads();
    for (int j = 0; j < 25; ++j)
      scT[t * 28 + j] = h1[((size_t)n * 100 + p0 + j) * 1024 + kc + t];
    __syncthreads();
    for (int k = 0; k < 256; ++k) {
      float wv = w2T[(size_t)(kc + k) * 256 + co];
      float v[28];
      const float* g = &scT[k * 28];
#pragma unroll
      for (int qq = 0; qq < 7; ++qq) *(float4*)&v[qq * 4] = *(const float4*)&g[qq * 4];
#pragma unroll
      for (int j = 0; j < 25; ++j) acc[j] = fmaf(wv, v[j], acc[j]);
    }
  }
#pragma unroll
  for (int j = 0; j < 25; ++j)
    h2[((size_t)n * 100 + p0 + j) * 256 + co] = fmaxf(acc[j], 0.0f);
}

// ======================= classifier layer 3 (256 -> 1) =======================
__global__ void cls3_k(const float* __restrict__ h2, const float* __restrict__ w3,
                       const float* __restrict__ b3, float* __restrict__ out) {
  int n = blockIdx.x, t = threadIdx.x;
  if (t < 100) {
    float acc = b3[0];
    const float* hp = &h2[((size_t)n * 100 + t) * 256];
    for (int k = 0; k < 256; ++k) acc = fmaf(hp[k], w3[k], acc);
    out[n * 100 + t] = acc;
  }
}

// ======================= launch =======================
extern "C" void kernel_launch(void* const* d_in, const int* in_sizes, int n_in,
                              void* d_out, int out_size, void* d_ws, size_t ws_size,
                              hipStream_t stream) {
  const float* sc      = (const float*)d_in[0];
  const float* oc      = (const float*)d_in[1];
  const float* pos     = (const float*)d_in[2];
  const float* mlp_w1  = (const float*)d_in[3];
  const float* mlp_b1  = (const float*)d_in[4];
  const float* mlp_w2  = (const float*)d_in[5];
  const float* mlp_b2  = (const float*)d_in[6];
  const float* conv1_w = (const float*)d_in[7];
  const float* conv1_b = (const float*)d_in[8];
  const float* conv2_w = (const float*)d_in[9];
  const float* conv2_b = (const float*)d_in[10];
  const float* convt_w = (const float*)d_in[11];
  const float* convt_b = (const float*)d_in[12];
  const float* sa_w1   = (const float*)d_in[13];
  const float* sa_b1   = (const float*)d_in[14];
  const float* sa_w2   = (const float*)d_in[15];
  const float* sa_b2   = (const float*)d_in[16];
  const float* sa_w3   = (const float*)d_in[17];
  const float* sa_b3   = (const float*)d_in[18];
  const float* sa_w4   = (const float*)d_in[19];
  const float* sa_b4   = (const float*)d_in[20];
  const float* cls_w1  = (const float*)d_in[21];
  const float* cls_b1  = (const float*)d_in[22];
  const float* cls_w2  = (const float*)d_in[23];
  const float* cls_b2  = (const float*)d_in[24];
  const float* cls_w3  = (const float*)d_in[25];
  const float* cls_b3  = (const float*)d_in[26];

  float* ws = (float*)d_ws;
  float* c1wT  = ws;                       // [2304][512]
  float* c2wT  = c1wT + 1179648;           // [4608][1024]
  float* ctwT  = c2wT + 4718592;           // [4][1024][512]
  float* saw2T = ctwT + 2097152;           // [64][128]
  float* saw3T = saw2T + 8192;             // [128][256]
  float* saw4T = saw3T + 32768;            // [256][512]
  float* cw1T  = saw4T + 131072;           // [1538][1024]
  float* cw2T  = cw1T + 1574912;           // [1024][256]
  float* mw2T  = cw2T + 262144;            // [128][256]
  float* vox   = mw2T + 32768;             // [32][20][20][256]  (K1 -> conv1)
  float* f1    = vox + 3276800;            // [32][10][10][512]
  float* obj   = f1 + 1638400;             // [32][512]
  float* ocm   = obj + 16384;              // [32][2]
  // lifetime-overlapped buffers:
  float* f3 = vox;                         // [32][10][10][512]  (convt -> cls1; vox dead)
  float* f2 = vox + 1638400;               // [32][5][5][1024]   (conv2 -> convt; vox dead)
  float* h1 = c1wT;                        // [32][100][1024]    (cls1 -> cls2; conv wT dead)
  float* h2 = ctwT;                        // [32][100][256]     (cls2 -> cls3; ctwT dead)
  float* outp = (float*)d_out;

  dim3 tb(32, 8);
  transpose_k<<<dim3(72, 16), tb, 0, stream>>>(conv1_w, c1wT, 512, 2304, 1, 0);
  transpose_k<<<dim3(144, 32), tb, 0, stream>>>(conv2_w, c2wT, 1024, 4608, 1, 0);
  for (int p = 0; p < 4; ++p)              // plane p=a*2+b holds W[o][i][1-a][1-b]
    transpose_k<<<dim3(32, 16), tb, 0, stream>>>(convt_w, ctwT + p * 524288, 512, 1024, 4, 3 - p);
  transpose_k<<<dim3(2, 4), tb, 0, stream>>>(sa_w2, saw2T, 128, 64, 1, 0);
  transpose_k<<<dim3(4, 8), tb, 0, stream>>>(sa_w3, saw3T, 256, 128, 1, 0);
  transpose_k<<<dim3(8, 16), tb, 0, stream>>>(sa_w4, saw4T, 512, 256, 1, 0);
  transpose_k<<<dim3(49, 32), tb, 0, stream>>>(cls_w1, cw1T, 1024, 1538, 1, 0);
  transpose_k<<<dim3(32, 8), tb, 0, stream>>>(cls_w2, cw2T, 256, 1024, 1, 0);
  transpose_k<<<dim3(4, 8), tb, 0, stream>>>(mlp_w2, mw2T, 256, 128, 1, 0);

  hipMemsetAsync(vox, 0, (size_t)3276800 * 4, stream);
  hipMemsetAsync(obj, 0, (size_t)16384 * 4, stream);
  ocmean_k<<<32, 256, 0, stream>>>(oc, ocm);

  pointnet_k<<<2048, 256, 0, stream>>>(sc, mlp_w1, mlp_b1, mw2T, mlp_b2, vox);
  conv1_k<<<1280, 256, 0, stream>>>(vox, c1wT, conv1_b, f1);
  conv2_k<<<1280, 256, 0, stream>>>(f1, c2wT, conv2_b, f2);
  convt_k<<<256, 256, 0, stream>>>(f2, ctwT, convt_b, f3);
  sa_k<<<2048, 256, 0, stream>>>(oc, ocm, sa_w1, sa_b1, saw2T, sa_b2,
                                 saw3T, sa_b3, saw4T, sa_b4, obj);
  cls1_k<<<256, 256, 0, stream>>>(f1, f3, obj, pos, cw1T, cls_b1, h1);
  cls2_k<<<128, 256, 0, stream>>>(h1, cw2T, cls_b2, h2);
  cls3_k<<<32, 128, 0, stream>>>(h2, cls_w3, cls_b3, outp);
}

// Round 3
// 1393.965 us; speedup vs baseline: 1.6101x; 1.6101x over previous
//
#include <hip/hip_runtime.h>

#define NB 32
#define PP 8192
#define OPP 2048

typedef _Float16 f16;
typedef f16 half8 __attribute__((ext_vector_type(8)));
typedef f16 half4 __attribute__((ext_vector_type(4)));
typedef float f32x4 __attribute__((ext_vector_type(4)));

// ======================= generic tiled transpose =======================
// out[j*R + i] = in[(i*C + j)*es + eo]
__global__ void transpose_k(const float* __restrict__ in, float* __restrict__ out,
                            int R, int C, int es, int eo) {
  __shared__ float tile[32][33];
  int jb = blockIdx.x * 32, ib = blockIdx.y * 32;
  int tx = threadIdx.x, ty = threadIdx.y;
  for (int yy = ty; yy < 32; yy += 8) {
    int i = ib + yy, j = jb + tx;
    if (i < R && j < C) tile[yy][tx] = in[((size_t)i * C + j) * (size_t)es + eo];
  }
  __syncthreads();
  for (int yy = ty; yy < 32; yy += 8) {
    int j = jb + yy, i = ib + tx;
    if (j < C && i < R) out[(size_t)j * R + i] = tile[tx][yy];
  }
}

// ======================= weight prep: [co][ci][3][3] fp32 -> [k][co][ci] fp16 ===========
template <int CO, int CI>
__global__ void wprep_k(const float* __restrict__ wsrc, f16* __restrict__ wdst) {
  int idx = blockIdx.x * 256 + threadIdx.x;
  if (idx >= 9 * CO * CI) return;
  int ci = idx & (CI - 1);
  int rem = idx / CI;
  int co = rem & (CO - 1);
  int k = rem / CO;
  wdst[idx] = (f16)wsrc[((size_t)co * CI + ci) * 9 + k];
}

// ======================= fp32 -> fp16 convert =======================
__global__ void cvt16_k(const float* __restrict__ in, f16* __restrict__ out, int n4) {
  int idx = blockIdx.x * 256 + threadIdx.x;
  if (idx >= n4) return;
  float4 v = ((const float4*)in)[idx];
  half4 h; h.x = (f16)v.x; h.y = (f16)v.y; h.z = (f16)v.z; h.w = (f16)v.w;
  ((half4*)out)[idx] = h;
}

// ======================= object-cloud mean =======================
__global__ void ocmean_k(const float* __restrict__ oc, float* __restrict__ ocm) {
  int n = blockIdx.x, t = threadIdx.x;
  __shared__ float sx[256], sy[256];
  float ax = 0.f, ay = 0.f;
  for (int p = t; p < OPP; p += 256) {
    ax += oc[((size_t)n * OPP + p) * 2 + 0];
    ay += oc[((size_t)n * OPP + p) * 2 + 1];
  }
  sx[t] = ax; sy[t] = ay;
  __syncthreads();
  for (int s = 128; s > 0; s >>= 1) {
    if (t < s) { sx[t] += sx[t + s]; sy[t] += sy[t + s]; }
    __syncthreads();
  }
  if (t == 0) {
    ocm[n * 2 + 0] = sx[0] / (float)OPP;
    ocm[n * 2 + 1] = sy[0] / (float)OPP;
  }
}

// ======================= voxel PointNet + scatter-max =======================
__global__ __launch_bounds__(256) void pointnet_k(
    const float* __restrict__ sc, const float* __restrict__ w1, const float* __restrict__ b1,
    const float* __restrict__ w2T, const float* __restrict__ b2, float* __restrict__ vox) {
  __shared__ float hT[128 * 20];
  __shared__ float pcx[16], pcy[16];
  __shared__ int binl[16];
  int t = threadIdx.x, lane = t & 63, w = t >> 6;
  int blk = blockIdx.x;
  int n = blk >> 6, pbase0 = (blk & 63) * 128;
  int o = w * 64 + lane;
  float b2o = b2[o];
  for (int it = 0; it < 8; ++it) {
    int pb = pbase0 + it * 16;
    if (t < 16) {
      float x = sc[((size_t)n * PP + pb + t) * 2 + 0];
      float y = sc[((size_t)n * PP + pb + t) * 2 + 1];
      float bif = fminf(fmaxf(ceilf((x + 0.5f) * 20.0f) - 1.0f, 0.0f), 19.0f);
      float bjf = fminf(fmaxf(ceilf((y + 0.5f) * 20.0f) - 1.0f, 0.0f), 19.0f);
      bool valid = (x > -0.5f) && (x <= 0.5f) && (y > -0.5f) && (y <= 0.5f);
      float ci = -0.5f + (bif + 0.5f) / 20.0f;
      float cj = -0.5f + (bjf + 0.5f) / 20.0f;
      pcx[t] = x - ci; pcy[t] = y - cj;
      binl[t] = valid ? ((int)bif * 20 + (int)bjf) : -1;
    }
    __syncthreads();
    {
      int c = t & 127, ph = t >> 7;
      float wx = w1[c * 2 + 0], wy = w1[c * 2 + 1], bb = b1[c];
#pragma unroll
      for (int j = 0; j < 8; ++j) {
        int p = ph * 8 + j;
        hT[c * 20 + p] = fmaxf(wx * pcx[p] + wy * pcy[p] + bb, 0.0f);
      }
    }
    __syncthreads();
    float acc[16];
#pragma unroll
    for (int j = 0; j < 16; ++j) acc[j] = 0.0f;
    for (int k = 0; k < 128; ++k) {
      float wv = w2T[k * 256 + o];
      float hv[16];
      *(float4*)&hv[0]  = *(const float4*)&hT[k * 20 + 0];
      *(float4*)&hv[4]  = *(const float4*)&hT[k * 20 + 4];
      *(float4*)&hv[8]  = *(const float4*)&hT[k * 20 + 8];
      *(float4*)&hv[12] = *(const float4*)&hT[k * 20 + 12];
#pragma unroll
      for (int j = 0; j < 16; ++j) acc[j] = fmaf(wv, hv[j], acc[j]);
    }
    size_t vbase = (size_t)n * 400 * 256 + o;
#pragma unroll
    for (int j = 0; j < 16; ++j) {
      int bn = binl[j];
      if (bn >= 0) {
        float v = fmaxf(acc[j] + b2o, 0.0f);
        atomicMax((int*)vox + vbase + (size_t)bn * 256, __float_as_int(v));
      }
    }
    __syncthreads();
  }
}

// ======================= MFMA implicit-GEMM conv 3x3 pad1 + relu (pre-pool out) ==========
// inh: [NB][H*W][CI] fp16 ; wh: [9][CO][CI] fp16 ; outh: [NB][H*W][CO] fp16
// Block: (n, m-split, co-group-of-128). 4 waves: wave n-range = 32 (2 n-tiles).
// LDS: A halo patch [PR][PC] pixels x 40 halves (80 B stride: 16B aligned, 2-way banks)
//      B tile 3 kx positions x 128 rows x 40 halves.
template <int H, int W, int CI, int CO, int MSPLIT>
__global__ __launch_bounds__(256, 1) void convmfma_k(
    const f16* __restrict__ inh, const f16* __restrict__ wh,
    const float* __restrict__ bias, f16* __restrict__ outh) {
  constexpr int HS = H / MSPLIT;
  constexpr int Mpix = HS * W;
  constexpr int MT = (Mpix + 15) / 16;
  constexpr int PR = HS + 2, PC = W + 2;
  constexpr int NCIC = CI / 32;
  constexpr int COG = CO / 128;
  extern __shared__ char smem[];
  f16* Ap = (f16*)smem;                          // [PR*PC][40]
  f16* Bp = (f16*)(smem + PR * PC * 80);         // [3*128][40]
  int b = blockIdx.x;
  int cog = b % COG;
  int ms = (b / COG) % MSPLIT;
  int n = b / (COG * MSPLIT);
  int co0 = cog * 128;
  int r0 = ms * HS;
  int t = threadIdx.x, lane = t & 63, w = t >> 6;
  int quad = lane >> 4, l16 = lane & 15;

  int abase[MT];
#pragma unroll
  for (int mi = 0; mi < MT; ++mi) {
    int pl = mi * 16 + l16; if (pl > Mpix - 1) pl = Mpix - 1;
    int y = pl / W, x = pl - y * W;
    abase[mi] = (y * PC + x) * 40 + quad * 8;    // halves
  }
  f32x4 zz = {0.f, 0.f, 0.f, 0.f};
  f32x4 acc[MT][2];
#pragma unroll
  for (int mi = 0; mi < MT; ++mi) { acc[mi][0] = zz; acc[mi][1] = zz; }

  const f16* inbase = inh + (size_t)n * H * W * CI;
  int nl = w * 32;

  for (int cic = 0; cic < NCIC; ++cic) {
    // ---- stage A (zero pad + interior in one pass) ----
    for (int cell = t; cell < PR * PC; cell += 256) {
      int pr = cell / PC, pc = cell - pr * PC;
      int yin = r0 - 1 + pr, xin = pc - 1;
      uint4 d0 = {0,0,0,0}, d1 = {0,0,0,0}, d2 = {0,0,0,0}, d3 = {0,0,0,0};
      if (yin >= 0 && yin < H && xin >= 0 && xin < W) {
        const uint4* src = (const uint4*)(inbase + ((size_t)yin * W + xin) * CI + cic * 32);
        d0 = src[0]; d1 = src[1]; d2 = src[2]; d3 = src[3];
      }
      uint4* dst = (uint4*)(Ap + cell * 40);
      dst[0] = d0; dst[1] = d1; dst[2] = d2; dst[3] = d3;
    }
    for (int ky = 0; ky < 3; ++ky) {
      // ---- stage B: 3 kx positions x 128 co rows ----
      for (int idx = t; idx < 3 * 128; idx += 256) {
        int kx = idx >> 7, cr = idx & 127;
        int k = ky * 3 + kx;
        const uint4* src = (const uint4*)(wh + ((size_t)k * CO + co0 + cr) * CI + cic * 32);
        uint4* dst = (uint4*)(Bp + idx * 40);
        dst[0] = src[0]; dst[1] = src[1]; dst[2] = src[2]; dst[3] = src[3];
      }
      __syncthreads();
#pragma unroll
      for (int kx = 0; kx < 3; ++kx) {
        int shift = (ky * PC + kx) * 40;
        half8 bf0 = *(const half8*)(Bp + (kx * 128 + nl + l16) * 40 + quad * 8);
        half8 bf1 = *(const half8*)(Bp + (kx * 128 + nl + 16 + l16) * 40 + quad * 8);
#pragma unroll
        for (int mi = 0; mi < MT; ++mi) {
          half8 af = *(const half8*)(Ap + abase[mi] + shift);
          acc[mi][0] = __builtin_amdgcn_mfma_f32_16x16x32_f16(af, bf0, acc[mi][0], 0, 0, 0);
          acc[mi][1] = __builtin_amdgcn_mfma_f32_16x16x32_f16(af, bf1, acc[mi][1], 0, 0, 0);
        }
      }
      __syncthreads();
    }
  }
  // ---- epilogue: bias + relu + fp16 store (pre-pool layout) ----
  int co_w = co0 + nl;
  float bv0 = bias[co_w + l16];
  float bv1 = bias[co_w + 16 + l16];
  f16* ob = outh + ((size_t)n * H * W + (size_t)ms * Mpix) * CO;
#pragma unroll
  for (int mi = 0; mi < MT; ++mi) {
#pragma unroll
    for (int r = 0; r < 4; ++r) {
      int p = mi * 16 + quad * 4 + r;
      if (p < Mpix) {
        float v0 = acc[mi][0][r] + bv0; v0 = v0 > 0.f ? v0 : 0.f;
        float v1 = acc[mi][1][r] + bv1; v1 = v1 > 0.f ? v1 : 0.f;
        ob[(size_t)p * CO + co_w + l16] = (f16)v0;
        ob[(size_t)p * CO + co_w + 16 + l16] = (f16)v1;
      }
    }
  }
}

// ======================= maxpool 2x2 (fp16 in) =======================
// g1 [NB][400][512] -> f1h [NB][100][512] fp16
__global__ void pool1_k(const f16* __restrict__ g1, f16* __restrict__ f1h) {
  int idx = blockIdx.x * 256 + threadIdx.x;
  if (idx >= 32 * 100 * 256) return;
  int c2 = idx & 255, rem = idx >> 8;
  int op = rem % 100, n = rem / 100;
  int py = op / 10, px = op - py * 10;
  const f16* base = g1 + (((size_t)n * 400 + (size_t)(2 * py) * 20 + 2 * px) * 512) + c2 * 2;
  float a0 = (float)base[0],   a1 = (float)base[1];
  float b0 = (float)base[512], b1 = (float)base[513];
  const f16* base2 = base + 20 * 512;
  float c0 = (float)base2[0],   c1 = (float)base2[1];
  float d0 = (float)base2[512], d1 = (float)base2[513];
  float m0 = fmaxf(fmaxf(a0, b0), fmaxf(c0, d0));
  float m1 = fmaxf(fmaxf(a1, b1), fmaxf(c1, d1));
  f16* o = f1h + ((size_t)n * 100 + op) * 512 + c2 * 2;
  o[0] = (f16)m0; o[1] = (f16)m1;
}

// g2 [NB][100][1024] fp16 -> f2 [NB][25][1024] fp32
__global__ void pool2_k(const f16* __restrict__ g2, float* __restrict__ f2) {
  int idx = blockIdx.x * 256 + threadIdx.x;
  if (idx >= 32 * 25 * 512) return;
  int c2 = idx & 511, rem = idx >> 9;
  int op = rem % 25, n = rem / 25;
  int py = op / 5, px = op - py * 5;
  const f16* base = g2 + (((size_t)n * 100 + (size_t)(2 * py) * 10 + 2 * px) * 1024) + c2 * 2;
  float a0 = (float)base[0],    a1 = (float)base[1];
  float b0 = (float)base[1024], b1 = (float)base[1025];
  const f16* base2 = base + 10 * 1024;
  float c0 = (float)base2[0],    c1 = (float)base2[1];
  float d0 = (float)base2[1024], d1 = (float)base2[1025];
  float* o = f2 + ((size_t)n * 25 + op) * 1024 + c2 * 2;
  o[0] = fmaxf(fmaxf(a0, b0), fmaxf(c0, d0));
  o[1] = fmaxf(fmaxf(a1, b1), fmaxf(c1, d1));
}

// ======================= conv transpose 2x2 s2 (1024->512) fp32 =======================
__global__ __launch_bounds__(256) void convt_k(
    const float* __restrict__ f2, const float* __restrict__ ctwT,
    const float* __restrict__ ctb, float* __restrict__ f3) {
  __shared__ float f2T[256 * 32];
  int b = blockIdx.x;
  int cog = b & 7, n = b >> 3;
  int t = threadIdx.x, lane = t & 63, w = t >> 6;
  int co = cog * 64 + lane;
  float acc[4][8];
#pragma unroll
  for (int a = 0; a < 4; ++a)
#pragma unroll
    for (int j = 0; j < 8; ++j) acc[a][j] = 0.0f;
  int px0 = w * 8;
  for (int ic = 0; ic < 4; ++ic) {
    __syncthreads();
    for (int i = t; i < 256 * 32; i += 256) f2T[i] = 0.0f;
    __syncthreads();
    for (int idx = t; idx < 25 * 256; idx += 256) {
      int px = idx >> 8, ii = idx & 255;
      f2T[ii * 32 + px] = f2[((size_t)n * 25 + px) * 1024 + ic * 256 + ii];
    }
    __syncthreads();
    for (int ii = 0; ii < 256; ++ii) {
      int i = ic * 256 + ii;
      float w0 = ctwT[((size_t)(0 * 1024 + i) * 512) + co];
      float w1v = ctwT[((size_t)(1 * 1024 + i) * 512) + co];
      float w2v = ctwT[((size_t)(2 * 1024 + i) * 512) + co];
      float w3v = ctwT[((size_t)(3 * 1024 + i) * 512) + co];
      float v[8];
      *(float4*)&v[0] = *(const float4*)&f2T[ii * 32 + px0];
      *(float4*)&v[4] = *(const float4*)&f2T[ii * 32 + px0 + 4];
#pragma unroll
      for (int j = 0; j < 8; ++j) {
        acc[0][j] = fmaf(w0, v[j], acc[0][j]);
        acc[1][j] = fmaf(w1v, v[j], acc[1][j]);
        acc[2][j] = fmaf(w2v, v[j], acc[2][j]);
        acc[3][j] = fmaf(w3v, v[j], acc[3][j]);
      }
    }
  }
  float bb = ctb[co];
#pragma unroll
  for (int ab = 0; ab < 4; ++ab) {
    int a = ab >> 1, bcol = ab & 1;
#pragma unroll
    for (int j = 0; j < 8; ++j) {
      int px = px0 + j;
      if (px < 25) {
        int ph = px / 5, pw = px - ph * 5;
        f3[(((size_t)n * 10 + 2 * ph + a) * 10 + 2 * pw + bcol) * 512 + co] = acc[ab][j] + bb;
      }
    }
  }
}

// ======================= object set-abstraction (fused 4 layers + max) =======================
__global__ __launch_bounds__(256) void sa_k(
    const float* __restrict__ oc, const float* __restrict__ ocm,
    const float* __restrict__ w1, const float* __restrict__ b1,
    const float* __restrict__ w2T, const float* __restrict__ b2,
    const float* __restrict__ w3T, const float* __restrict__ b3,
    const float* __restrict__ w4T, const float* __restrict__ b4,
    float* __restrict__ obj) {
  __shared__ float g1T[64 * 36];
  __shared__ float g2T[128 * 36];
  __shared__ float g3T[256 * 36];
  __shared__ float pcx[32], pcy[32];
  int b = blockIdx.x;
  int n = b >> 6, pb = (b & 63) * 32;
  int t = threadIdx.x;
  if (t < 32) {
    pcx[t] = oc[((size_t)n * OPP + pb + t) * 2 + 0] - ocm[n * 2 + 0];
    pcy[t] = oc[((size_t)n * OPP + pb + t) * 2 + 1] - ocm[n * 2 + 1];
  }
  __syncthreads();
  {
    int c = t & 63, pj = t >> 6;
    float wx = w1[c * 2], wy = w1[c * 2 + 1], bb = b1[c];
#pragma unroll
    for (int j = 0; j < 8; ++j) {
      int p = pj * 8 + j;
      g1T[c * 36 + p] = fmaxf(fmaf(wx, pcx[p], fmaf(wy, pcy[p], bb)), 0.0f);
    }
  }
  __syncthreads();
  {
    int c = t & 127, ph = t >> 7;
    float acc[16];
#pragma unroll
    for (int j = 0; j < 16; ++j) acc[j] = 0.0f;
    for (int k = 0; k < 64; ++k) {
      float wv = w2T[k * 128 + c];
      float v[16];
      const float* g = &g1T[k * 36 + ph * 16];
#pragma unroll
      for (int q = 0; q < 4; ++q) *(float4*)&v[q * 4] = *(const float4*)&g[q * 4];
#pragma unroll
      for (int j = 0; j < 16; ++j) acc[j] = fmaf(wv, v[j], acc[j]);
    }
    float bb = b2[c];
#pragma unroll
    for (int j = 0; j < 16; ++j) g2T[c * 36 + ph * 16 + j] = fmaxf(acc[j] + bb, 0.0f);
  }
  __syncthreads();
  {
    int c = t;
    float acc[32];
#pragma unroll
    for (int j = 0; j < 32; ++j) acc[j] = 0.0f;
    for (int k = 0; k < 128; ++k) {
      float wv = w3T[k * 256 + c];
      float v[32];
      const float* g = &g2T[k * 36];
#pragma unroll
      for (int q = 0; q < 8; ++q) *(float4*)&v[q * 4] = *(const float4*)&g[q * 4];
#pragma unroll
      for (int j = 0; j < 32; ++j) acc[j] = fmaf(wv, v[j], acc[j]);
    }
    float bb = b3[c];
#pragma unroll
    for (int j = 0; j < 32; ++j) g3T[c * 36 + j] = fmaxf(acc[j] + bb, 0.0f);
  }
  __syncthreads();
  {
    int c0 = t, c1 = t + 256;
    float a0[32], a1[32];
#pragma unroll
    for (int j = 0; j < 32; ++j) { a0[j] = 0.0f; a1[j] = 0.0f; }
    for (int k = 0; k < 256; ++k) {
      float wv0 = w4T[k * 512 + c0];
      float wv1 = w4T[k * 512 + c1];
      float v[32];
      const float* g = &g3T[k * 36];
#pragma unroll
      for (int q = 0; q < 8; ++q) *(float4*)&v[q * 4] = *(const float4*)&g[q * 4];
#pragma unroll
      for (int j = 0; j < 32; ++j) {
        a0[j] = fmaf(wv0, v[j], a0[j]);
        a1[j] = fmaf(wv1, v[j], a1[j]);
      }
    }
    float m0 = a0[0], m1 = a1[0];
#pragma unroll
    for (int j = 1; j < 32; ++j) { m0 = fmaxf(m0, a0[j]); m1 = fmaxf(m1, a1[j]); }
    m0 = fmaxf(m0 + b4[c0], 0.0f);
    m1 = fmaxf(m1 + b4[c1], 0.0f);
    atomicMax((int*)obj + (size_t)n * 512 + c0, __float_as_int(m0));
    atomicMax((int*)obj + (size_t)n * 512 + c1, __float_as_int(m1));
  }
}

// ======================= classifier layer 1 (1538 -> 1024) =======================
__global__ __launch_bounds__(256) void cls1_k(
    const f16* __restrict__ f1h, const float* __restrict__ f3, const float* __restrict__ obj,
    const float* __restrict__ pos, const float* __restrict__ w1T, const float* __restrict__ b1,
    f16* __restrict__ h1h) {
  __shared__ float scT[256 * 52];
  int b = blockIdx.x;
  int cg = b & 3, half = (b >> 2) & 1, n = b >> 3;
  int t = threadIdx.x, lane = t & 63, w = t >> 6;
  int co = cg * 256 + w * 64 + lane;
  int p0 = half * 50;
  float od = 0.0f;
  for (int k = 0; k < 512; ++k)
    od = fmaf(obj[(size_t)n * 512 + k], w1T[(size_t)(1024 + k) * 1024 + co], od);
  float w1536 = w1T[(size_t)1536 * 1024 + co];
  float w1537 = w1T[(size_t)1537 * 1024 + co];
  float posx = pos[n * 2 + 0], posy = pos[n * 2 + 1];
  float bb = b1[co];
  float acc[50];
#pragma unroll
  for (int j = 0; j < 50; ++j) {
    int px = p0 + j;
    int row = px / 10, col = px - row * 10;
    float relx = posx - (-0.5f + (row + 0.5f) / 10.0f);
    float rely = posy - (-0.5f + (col + 0.5f) / 10.0f);
    acc[j] = od + bb + relx * w1536 + rely * w1537;
  }
  for (int kc = 0; kc < 1024; kc += 256) {
    __syncthreads();
    int kk = (kc & 511) + t;
    if (kc < 512) {
      for (int j = 0; j < 50; ++j)
        scT[t * 52 + j] = (float)f1h[((size_t)n * 100 + p0 + j) * 512 + kk];
    } else {
      for (int j = 0; j < 50; ++j)
        scT[t * 52 + j] = f3[((size_t)n * 100 + p0 + j) * 512 + kk];
    }
    __syncthreads();
    for (int k = 0; k < 256; ++k) {
      float wv = w1T[(size_t)(kc + k) * 1024 + co];
      float v[52];
      const float* g = &scT[k * 52];
#pragma unroll
      for (int q = 0; q < 13; ++q) *(float4*)&v[q * 4] = *(const float4*)&g[q * 4];
#pragma unroll
      for (int j = 0; j < 50; ++j) acc[j] = fmaf(wv, v[j], acc[j]);
    }
  }
#pragma unroll
  for (int j = 0; j < 50; ++j)
    h1h[((size_t)n * 100 + p0 + j) * 1024 + co] = (f16)fmaxf(acc[j], 0.0f);
}

// ======================= classifier layer 2 (1024 -> 256) =======================
__global__ __launch_bounds__(256) void cls2_k(
    const f16* __restrict__ h1h, const float* __restrict__ w2T,
    const float* __restrict__ b2, float* __restrict__ h2) {
  __shared__ float scT[256 * 28];
  int b = blockIdx.x;
  int q = b & 3, n = b >> 2;
  int t = threadIdx.x, lane = t & 63, w = t >> 6;
  int co = w * 64 + lane;
  int p0 = q * 25;
  float acc[25];
  float bb = b2[co];
#pragma unroll
  for (int j = 0; j < 25; ++j) acc[j] = bb;
  for (int kc = 0; kc < 1024; kc += 256) {
    __syncthreads();
    for (int j = 0; j < 25; ++j)
      scT[t * 28 + j] = (float)h1h[((size_t)n * 100 + p0 + j) * 1024 + kc + t];
    __syncthreads();
    for (int k = 0; k < 256; ++k) {
      float wv = w2T[(size_t)(kc + k) * 256 + co];
      float v[28];
      const float* g = &scT[k * 28];
#pragma unroll
      for (int qq = 0; qq < 7; ++qq) *(float4*)&v[qq * 4] = *(const float4*)&g[qq * 4];
#pragma unroll
      for (int j = 0; j < 25; ++j) acc[j] = fmaf(wv, v[j], acc[j]);
    }
  }
#pragma unroll
  for (int j = 0; j < 25; ++j)
    h2[((size_t)n * 100 + p0 + j) * 256 + co] = fmaxf(acc[j], 0.0f);
}

// ======================= classifier layer 3 (256 -> 1) =======================
__global__ void cls3_k(const float* __restrict__ h2, const float* __restrict__ w3,
                       const float* __restrict__ b3, float* __restrict__ out) {
  int n = blockIdx.x, t = threadIdx.x;
  if (t < 100) {
    float acc = b3[0];
    const float* hp = &h2[((size_t)n * 100 + t) * 256];
    for (int k = 0; k < 256; ++k) acc = fmaf(hp[k], w3[k], acc);
    out[n * 100 + t] = acc;
  }
}

// ======================= launch =======================
extern "C" void kernel_launch(void* const* d_in, const int* in_sizes, int n_in,
                              void* d_out, int out_size, void* d_ws, size_t ws_size,
                              hipStream_t stream) {
  const float* sc      = (const float*)d_in[0];
  const float* oc      = (const float*)d_in[1];
  const float* pos     = (const float*)d_in[2];
  const float* mlp_w1  = (const float*)d_in[3];
  const float* mlp_b1  = (const float*)d_in[4];
  const float* mlp_w2  = (const float*)d_in[5];
  const float* mlp_b2  = (const float*)d_in[6];
  const float* conv1_w = (const float*)d_in[7];
  const float* conv1_b = (const float*)d_in[8];
  const float* conv2_w = (const float*)d_in[9];
  const float* conv2_b = (const float*)d_in[10];
  const float* convt_w = (const float*)d_in[11];
  const float* convt_b = (const float*)d_in[12];
  const float* sa_w1   = (const float*)d_in[13];
  const float* sa_b1   = (const float*)d_in[14];
  const float* sa_w2   = (const float*)d_in[15];
  const float* sa_b2   = (const float*)d_in[16];
  const float* sa_w3   = (const float*)d_in[17];
  const float* sa_b3   = (const float*)d_in[18];
  const float* sa_w4   = (const float*)d_in[19];
  const float* sa_b4   = (const float*)d_in[20];
  const float* cls_w1  = (const float*)d_in[21];
  const float* cls_b1  = (const float*)d_in[22];
  const float* cls_w2  = (const float*)d_in[23];
  const float* cls_b2  = (const float*)d_in[24];
  const float* cls_w3  = (const float*)d_in[25];
  const float* cls_b3  = (const float*)d_in[26];

  float* ws = (float*)d_ws;
  // ---- workspace layout (floats) ----
  float* ctwT  = ws;                       // 2,097,152  (reused as h2 after convt)
  float* saw2T = ctwT + 2097152;           // 8,192
  float* saw3T = saw2T + 8192;             // 32,768
  float* saw4T = saw3T + 32768;            // 131,072
  float* cw1T  = saw4T + 131072;           // 1,574,912
  float* cw2T  = cw1T + 1574912;           // 262,144
  float* mw2T  = cw2T + 262144;            // 32,768
  f16*   w1h   = (f16*)(mw2T + 32768);     // 1,179,648 halves (589,824 f)
  f16*   w2h   = (f16*)((float*)w1h + 589824); // 4,718,592 halves (2,359,296 f) -> h1h reuse
  float* R     = (float*)w2h + 2359296;    // 3,276,800  vox -> g1buf -> {f2, f3}
  float* S     = R + 3276800;              // 1,638,400  voxh -> g2buf
  f16*   f1h   = (f16*)(S + 1638400);      // 1,638,400 halves (819,200 f)  [BUGFIX: was 409,600 f]
  float* obj   = (float*)f1h + 819200;     // 16,384
  float* ocm   = obj + 16384;              // 64

  float* vox   = R;
  f16*   g1buf = (f16*)R;
  float* f2    = R;
  float* f3    = R + 819200;
  f16*   voxh  = (f16*)S;
  f16*   g2buf = (f16*)S;
  f16*   h1h   = w2h;                      // w2h dead after conv2
  float* h2    = ctwT;                     // ctwT dead after convt
  float* outp  = (float*)d_out;

  dim3 tb(32, 8);
  // ---- weight preps ----
  for (int p = 0; p < 4; ++p)              // plane p=a*2+b holds W[o][i][1-a][1-b]
    transpose_k<<<dim3(32, 16), tb, 0, stream>>>(convt_w, ctwT + p * 524288, 512, 1024, 4, 3 - p);
  transpose_k<<<dim3(2, 4), tb, 0, stream>>>(sa_w2, saw2T, 128, 64, 1, 0);
  transpose_k<<<dim3(4, 8), tb, 0, stream>>>(sa_w3, saw3T, 256, 128, 1, 0);
  transpose_k<<<dim3(8, 16), tb, 0, stream>>>(sa_w4, saw4T, 512, 256, 1, 0);
  transpose_k<<<dim3(49, 32), tb, 0, stream>>>(cls_w1, cw1T, 1024, 1538, 1, 0);
  transpose_k<<<dim3(32, 8), tb, 0, stream>>>(cls_w2, cw2T, 256, 1024, 1, 0);
  transpose_k<<<dim3(4, 8), tb, 0, stream>>>(mlp_w2, mw2T, 256, 128, 1, 0);
  wprep_k<512, 256><<<4608, 256, 0, stream>>>(conv1_w, w1h);
  wprep_k<1024, 512><<<18432, 256, 0, stream>>>(conv2_w, w2h);

  hipMemsetAsync(vox, 0, (size_t)3276800 * 4, stream);
  hipMemsetAsync(obj, 0, (size_t)16384 * 4, stream);
  ocmean_k<<<32, 256, 0, stream>>>(oc, ocm);

  pointnet_k<<<2048, 256, 0, stream>>>(sc, mlp_w1, mlp_b1, mw2T, mlp_b2, vox);
  cvt16_k<<<3200, 256, 0, stream>>>(vox, voxh, 819200);

  // conv1: H=20 W=20 CI=256 CO=512, MSPLIT=4 -> 512 blocks; LDS = (7*22+384)*80
  convmfma_k<20, 20, 256, 512, 4><<<512, 256, (7 * 22 + 384) * 80, stream>>>(
      voxh, w1h, conv1_b, g1buf);
  pool1_k<<<3200, 256, 0, stream>>>(g1buf, f1h);
  // conv2: H=10 W=10 CI=512 CO=1024, MSPLIT=2 -> 512 blocks; LDS = (7*12+384)*80
  convmfma_k<10, 10, 512, 1024, 2><<<512, 256, (7 * 12 + 384) * 80, stream>>>(
      f1h, w2h, conv2_b, g2buf);
  pool2_k<<<1600, 256, 0, stream>>>(g2buf, f2);

  convt_k<<<256, 256, 0, stream>>>(f2, ctwT, convt_b, f3);
  sa_k<<<2048, 256, 0, stream>>>(oc, ocm, sa_w1, sa_b1, saw2T, sa_b2,
                                 saw3T, sa_b3, saw4T, sa_b4, obj);
  cls1_k<<<256, 256, 0, stream>>>(f1h, f3, obj, pos, cw1T, cls_b1, h1h);
  cls2_k<<<128, 256, 0, stream>>>(h1h, cw2T, cls_b2, h2);
  cls3_k<<<32, 128, 0, stream>>>(h2, cls_w3, cls_b3, outp);
}

// Round 4
// 898.951 us; speedup vs baseline: 2.4967x; 1.5507x over previous
//
#include <hip/hip_runtime.h>

#define NB 32
#define PP 8192
#define OPP 2048

typedef _Float16 f16;
typedef f16 half8 __attribute__((ext_vector_type(8)));
typedef f16 half4 __attribute__((ext_vector_type(4)));
typedef float f32x4 __attribute__((ext_vector_type(4)));

#define MFMA16(a, b, c) __builtin_amdgcn_mfma_f32_16x16x32_f16(a, b, c, 0, 0, 0)

// ======================= generic tiled transpose (fp32) =======================
__global__ void transpose_k(const float* __restrict__ in, float* __restrict__ out,
                            int R, int C, int es, int eo) {
  __shared__ float tile[32][33];
  int jb = blockIdx.x * 32, ib = blockIdx.y * 32;
  int tx = threadIdx.x, ty = threadIdx.y;
  for (int yy = ty; yy < 32; yy += 8) {
    int i = ib + yy, j = jb + tx;
    if (i < R && j < C) tile[yy][tx] = in[((size_t)i * C + j) * (size_t)es + eo];
  }
  __syncthreads();
  for (int yy = ty; yy < 32; yy += 8) {
    int j = jb + yy, i = ib + tx;
    if (j < C && i < R) out[(size_t)j * R + i] = tile[tx][yy];
  }
}

// ======================= weight preps =======================
template <int CO, int CI>
__global__ void wprep_k(const float* __restrict__ wsrc, f16* __restrict__ wdst) {
  int idx = blockIdx.x * 256 + threadIdx.x;
  if (idx >= 9 * CO * CI) return;
  int ci = idx & (CI - 1);
  int rem = idx / CI;
  int co = rem & (CO - 1);
  int k = rem / CO;
  wdst[idx] = (f16)wsrc[((size_t)co * CI + ci) * 9 + k];
}

__global__ void cvt16_k(const float* __restrict__ in, f16* __restrict__ out, int n4) {
  int idx = blockIdx.x * 256 + threadIdx.x;
  if (idx >= n4) return;
  float4 v = ((const float4*)in)[idx];
  half4 h; h.x = (f16)v.x; h.y = (f16)v.y; h.z = (f16)v.z; h.w = (f16)v.w;
  ((half4*)out)[idx] = h;
}

// cls_w1 scene part [1024][1538] -> [1024][1024] fp16
__global__ void cw1prep_k(const float* __restrict__ w, f16* __restrict__ out) {
  int idx = blockIdx.x * 256 + threadIdx.x;
  if (idx >= 1024 * 1024) return;
  int co = idx >> 10, k = idx & 1023;
  out[idx] = (f16)w[(size_t)co * 1538 + k];
}

// convt_w [o][i][a'][b'] -> ctwh[(p*512+o)*1024+i] = w[o][i][3-p] fp16
__global__ void ctprep_k(const float* __restrict__ w, f16* __restrict__ out) {
  int idx = blockIdx.x * 256 + threadIdx.x;
  if (idx >= 2048 * 1024) return;
  int np = idx >> 10, i = idx & 1023;
  int p = np >> 9, o = np & 511;
  out[idx] = (f16)w[((size_t)o * 1024 + i) * 4 + (3 - p)];
}

// ======================= object-cloud mean =======================
__global__ void ocmean_k(const float* __restrict__ oc, float* __restrict__ ocm) {
  int n = blockIdx.x, t = threadIdx.x;
  __shared__ float sx[256], sy[256];
  float ax = 0.f, ay = 0.f;
  for (int p = t; p < OPP; p += 256) {
    ax += oc[((size_t)n * OPP + p) * 2 + 0];
    ay += oc[((size_t)n * OPP + p) * 2 + 1];
  }
  sx[t] = ax; sy[t] = ay;
  __syncthreads();
  for (int s = 128; s > 0; s >>= 1) {
    if (t < s) { sx[t] += sx[t + s]; sy[t] += sy[t + s]; }
    __syncthreads();
  }
  if (t == 0) {
    ocm[n * 2 + 0] = sx[0] / (float)OPP;
    ocm[n * 2 + 1] = sy[0] / (float)OPP;
  }
}

// ======================= voxel PointNet (MFMA feat) + scatter-max =======================
// vox layout NHWC fp32: [n][bi][bj][256]
__global__ __launch_bounds__(256) void pointnet_mfma_k(
    const float* __restrict__ sc, const float* __restrict__ w1, const float* __restrict__ b1,
    const f16* __restrict__ w2h, const float* __restrict__ b2, float* __restrict__ vox) {
  __shared__ f16 hA[16 * 136];             // [pt][k], stride 136 halves
  __shared__ float pcx[16], pcy[16];
  __shared__ int binl[16];
  int t = threadIdx.x, lane = t & 63, w = t >> 6;
  int quad = lane >> 4, l16 = lane & 15;
  int blk = blockIdx.x;                    // 2048 = 32 n * 64 chunks
  int n = blk >> 6, pbase0 = (blk & 63) * 128;
  int n0 = w * 64;
  float bias[4];
#pragma unroll
  for (int nt = 0; nt < 4; ++nt) bias[nt] = b2[n0 + nt * 16 + l16];
  for (int it = 0; it < 8; ++it) {
    int pb = pbase0 + it * 16;
    if (t < 16) {
      float x = sc[((size_t)n * PP + pb + t) * 2 + 0];
      float y = sc[((size_t)n * PP + pb + t) * 2 + 1];
      float bif = fminf(fmaxf(ceilf((x + 0.5f) * 20.0f) - 1.0f, 0.0f), 19.0f);
      float bjf = fminf(fmaxf(ceilf((y + 0.5f) * 20.0f) - 1.0f, 0.0f), 19.0f);
      bool valid = (x > -0.5f) && (x <= 0.5f) && (y > -0.5f) && (y <= 0.5f);
      float ci = -0.5f + (bif + 0.5f) / 20.0f;
      float cj = -0.5f + (bjf + 0.5f) / 20.0f;
      pcx[t] = x - ci; pcy[t] = y - cj;
      binl[t] = valid ? ((int)bif * 20 + (int)bjf) : -1;
    }
    __syncthreads();
    {                                      // h layer 2->128
      int c = t & 127, pg = t >> 7;
      float wx = w1[c * 2 + 0], wy = w1[c * 2 + 1], bb = b1[c];
#pragma unroll
      for (int j = 0; j < 8; ++j) {
        int p = pg * 8 + j;
        hA[p * 136 + c] = (f16)fmaxf(wx * pcx[p] + wy * pcy[p] + bb, 0.0f);
      }
    }
    __syncthreads();
    f32x4 acc[4] = {};
#pragma unroll
    for (int ks = 0; ks < 4; ++ks) {
      half8 a = *(const half8*)(hA + l16 * 136 + ks * 32 + quad * 8);
#pragma unroll
      for (int nt = 0; nt < 4; ++nt) {
        half8 bf = *(const half8*)(w2h + (size_t)(n0 + nt * 16 + l16) * 128 + ks * 32 + quad * 8);
        acc[nt] = MFMA16(a, bf, acc[nt]);
      }
    }
    size_t vb = (size_t)n * 102400;
#pragma unroll
    for (int nt = 0; nt < 4; ++nt) {
      int ch = n0 + nt * 16 + l16;
#pragma unroll
      for (int r = 0; r < 4; ++r) {
        int p = quad * 4 + r;
        int bn = binl[p];
        if (bn >= 0) {
          float v = fmaxf(acc[nt][r] + bias[nt], 0.0f);
          atomicMax((int*)vox + vb + (size_t)bn * 256 + ch, __float_as_int(v));
        }
      }
    }
    __syncthreads();
  }
}

// ======================= MFMA implicit-GEMM conv 3x3 pad1 + relu =======================
template <int H, int W, int CI, int CO, int MSPLIT>
__global__ __launch_bounds__(256, 1) void convmfma_k(
    const f16* __restrict__ inh, const f16* __restrict__ wh,
    const float* __restrict__ bias, f16* __restrict__ outh) {
  constexpr int HS = H / MSPLIT;
  constexpr int Mpix = HS * W;
  constexpr int MT = (Mpix + 15) / 16;
  constexpr int PR = HS + 2, PC = W + 2;
  constexpr int NCIC = CI / 32;
  constexpr int COG = CO / 128;
  extern __shared__ char smem[];
  f16* Ap = (f16*)smem;                          // [PR*PC][40]
  f16* Bp = (f16*)(smem + PR * PC * 80);         // [3*128][40]
  int b = blockIdx.x;
  int cog = b % COG;
  int ms = (b / COG) % MSPLIT;
  int n = b / (COG * MSPLIT);
  int co0 = cog * 128;
  int r0 = ms * HS;
  int t = threadIdx.x, lane = t & 63, w = t >> 6;
  int quad = lane >> 4, l16 = lane & 15;

  int abase[MT];
#pragma unroll
  for (int mi = 0; mi < MT; ++mi) {
    int pl = mi * 16 + l16; if (pl > Mpix - 1) pl = Mpix - 1;
    int y = pl / W, x = pl - y * W;
    abase[mi] = (y * PC + x) * 40 + quad * 8;    // halves
  }
  f32x4 acc[MT][2] = {};

  const f16* inbase = inh + (size_t)n * H * W * CI;
  int nl = w * 32;

  for (int cic = 0; cic < NCIC; ++cic) {
    for (int cell = t; cell < PR * PC; cell += 256) {
      int pr = cell / PC, pc = cell - pr * PC;
      int yin = r0 - 1 + pr, xin = pc - 1;
      uint4 d0 = {0,0,0,0}, d1 = {0,0,0,0}, d2 = {0,0,0,0}, d3 = {0,0,0,0};
      if (yin >= 0 && yin < H && xin >= 0 && xin < W) {
        const uint4* src = (const uint4*)(inbase + ((size_t)yin * W + xin) * CI + cic * 32);
        d0 = src[0]; d1 = src[1]; d2 = src[2]; d3 = src[3];
      }
      uint4* dst = (uint4*)(Ap + cell * 40);
      dst[0] = d0; dst[1] = d1; dst[2] = d2; dst[3] = d3;
    }
    for (int ky = 0; ky < 3; ++ky) {
      for (int idx = t; idx < 3 * 128; idx += 256) {
        int kx = idx >> 7, cr = idx & 127;
        int k = ky * 3 + kx;
        const uint4* src = (const uint4*)(wh + ((size_t)k * CO + co0 + cr) * CI + cic * 32);
        uint4* dst = (uint4*)(Bp + idx * 40);
        dst[0] = src[0]; dst[1] = src[1]; dst[2] = src[2]; dst[3] = src[3];
      }
      __syncthreads();
#pragma unroll
      for (int kx = 0; kx < 3; ++kx) {
        int shift = (ky * PC + kx) * 40;
        half8 bf0 = *(const half8*)(Bp + (kx * 128 + nl + l16) * 40 + quad * 8);
        half8 bf1 = *(const half8*)(Bp + (kx * 128 + nl + 16 + l16) * 40 + quad * 8);
#pragma unroll
        for (int mi = 0; mi < MT; ++mi) {
          half8 af = *(const half8*)(Ap + abase[mi] + shift);
          acc[mi][0] = MFMA16(af, bf0, acc[mi][0]);
          acc[mi][1] = MFMA16(af, bf1, acc[mi][1]);
        }
      }
      __syncthreads();
    }
  }
  int co_w = co0 + nl;
  float bv0 = bias[co_w + l16];
  float bv1 = bias[co_w + 16 + l16];
  f16* ob = outh + ((size_t)n * H * W + (size_t)ms * Mpix) * CO;
#pragma unroll
  for (int mi = 0; mi < MT; ++mi) {
#pragma unroll
    for (int r = 0; r < 4; ++r) {
      int p = mi * 16 + quad * 4 + r;
      if (p < Mpix) {
        float v0 = acc[mi][0][r] + bv0; v0 = v0 > 0.f ? v0 : 0.f;
        float v1 = acc[mi][1][r] + bv1; v1 = v1 > 0.f ? v1 : 0.f;
        ob[(size_t)p * CO + co_w + l16] = (f16)v0;
        ob[(size_t)p * CO + co_w + 16 + l16] = (f16)v1;
      }
    }
  }
}

// ======================= maxpool 2x2 =======================
__global__ void pool1_k(const f16* __restrict__ g1, f16* __restrict__ f1h) {
  int idx = blockIdx.x * 256 + threadIdx.x;
  if (idx >= 32 * 100 * 256) return;
  int c2 = idx & 255, rem = idx >> 8;
  int op = rem % 100, n = rem / 100;
  int py = op / 10, px = op - py * 10;
  const f16* base = g1 + (((size_t)n * 400 + (size_t)(2 * py) * 20 + 2 * px) * 512) + c2 * 2;
  float a0 = (float)base[0],   a1 = (float)base[1];
  float b0 = (float)base[512], b1 = (float)base[513];
  const f16* base2 = base + 20 * 512;
  float c0 = (float)base2[0],   c1 = (float)base2[1];
  float d0 = (float)base2[512], d1 = (float)base2[513];
  f16* o = f1h + ((size_t)n * 100 + op) * 512 + c2 * 2;
  o[0] = (f16)fmaxf(fmaxf(a0, b0), fmaxf(c0, d0));
  o[1] = (f16)fmaxf(fmaxf(a1, b1), fmaxf(c1, d1));
}

__global__ void pool2_k(const f16* __restrict__ g2, f16* __restrict__ f2h) {
  int idx = blockIdx.x * 256 + threadIdx.x;
  if (idx >= 32 * 25 * 512) return;
  int c2 = idx & 511, rem = idx >> 9;
  int op = rem % 25, n = rem / 25;
  int py = op / 5, px = op - py * 5;
  const f16* base = g2 + (((size_t)n * 100 + (size_t)(2 * py) * 10 + 2 * px) * 1024) + c2 * 2;
  float a0 = (float)base[0],    a1 = (float)base[1];
  float b0 = (float)base[1024], b1 = (float)base[1025];
  const f16* base2 = base + 10 * 1024;
  float c0 = (float)base2[0],    c1 = (float)base2[1];
  float d0 = (float)base2[1024], d1 = (float)base2[1025];
  f16* o = f2h + ((size_t)n * 25 + op) * 1024 + c2 * 2;
  o[0] = (f16)fmaxf(fmaxf(a0, b0), fmaxf(c0, d0));
  o[1] = (f16)fmaxf(fmaxf(a1, b1), fmaxf(c1, d1));
}

// ======================= pack f1 into scene buffer =======================
// scnh [n][100][1024]: cols 0..511 = f1, 512..1023 = f3 (written by convt)
__global__ void pack_k(const f16* __restrict__ f1h, f16* __restrict__ scnh) {
  int idx = blockIdx.x * 256 + threadIdx.x;
  if (idx >= 204800) return;                     // 32*100*512/8
  int c8 = idx & 63, row = idx >> 6;
  *(half8*)(scnh + (size_t)row * 1024 + c8 * 8) =
      *(const half8*)(f1h + (size_t)row * 512 + c8 * 8);
}

// ======================= conv transpose 2x2 s2 (1024->512), MFMA =======================
__global__ __launch_bounds__(256, 1) void convt_mfma_k(
    const f16* __restrict__ f2h, const f16* __restrict__ ctwh,
    const float* __restrict__ ctb, f16* __restrict__ scnh) {
  __shared__ f16 act[32 * 72];
  int b = blockIdx.x;                      // 64 = 32 n * 2 halves
  int nh = b & 1, n = b >> 1;
  int t = threadIdx.x, lane = t & 63, w = t >> 6;
  int quad = lane >> 4, l16 = lane & 15;
  f32x4 acc[2][16] = {};
  for (int kc = 0; kc < 16; ++kc) {
    int k0 = kc * 64;
    __syncthreads();
    {
      int row = t >> 3, c8 = t & 7;        // 256 items exactly
      half8 v = {};
      if (row < 25) v = *(const half8*)(f2h + ((size_t)n * 25 + row) * 1024 + k0 + c8 * 8);
      *(half8*)(act + row * 72 + c8 * 8) = v;
    }
    __syncthreads();
#pragma unroll
    for (int ks = 0; ks < 2; ++ks) {
      half8 a0 = *(const half8*)(act + l16 * 72 + ks * 32 + quad * 8);
      half8 a1 = *(const half8*)(act + (16 + l16) * 72 + ks * 32 + quad * 8);
#pragma unroll
      for (int nt = 0; nt < 16; ++nt) {
        half8 bf = *(const half8*)(ctwh +
            (size_t)(nh * 1024 + w * 256 + nt * 16 + l16) * 1024 + k0 + ks * 32 + quad * 8);
        acc[0][nt] = MFMA16(a0, bf, acc[0][nt]);
        acc[1][nt] = MFMA16(a1, bf, acc[1][nt]);
      }
    }
  }
#pragma unroll
  for (int nt = 0; nt < 16; ++nt) {
    int np = nh * 1024 + w * 256 + nt * 16 + l16;
    int p = np >> 9, co = np & 511;
    int a = p >> 1, bc = p & 1;
    float bb = ctb[co];
#pragma unroll
    for (int mt = 0; mt < 2; ++mt)
#pragma unroll
      for (int r = 0; r < 4; ++r) {
        int px = mt * 16 + quad * 4 + r;
        if (px < 25) {
          int ph = px / 5, pw = px - ph * 5;
          int opx = (2 * ph + a) * 10 + 2 * pw + bc;
          scnh[((size_t)n * 100 + opx) * 1024 + 512 + co] = (f16)(acc[mt][nt][r] + bb);
        }
      }
  }
}

// ======================= object SA: fused 4-layer MFMA + max =======================
__global__ __launch_bounds__(256) void sa_mfma_k(
    const float* __restrict__ oc, const float* __restrict__ ocm,
    const float* __restrict__ w1, const float* __restrict__ b1,
    const f16* __restrict__ w2h, const float* __restrict__ b2,
    const f16* __restrict__ w3h, const float* __restrict__ b3,
    const f16* __restrict__ w4h, const float* __restrict__ b4,
    float* __restrict__ obj) {
  __shared__ f16 act1[32 * 72];            // [pt][K=64]
  __shared__ f16 act2[32 * 136];           // [pt][K=128]
  __shared__ f16 act3[32 * 264];           // [pt][K=256]
  __shared__ float pcx[32], pcy[32];
  int b = blockIdx.x;                      // 2048 = 32 n * 64 chunks of 32 pts
  int n = b >> 6, pb = (b & 63) * 32;
  int t = threadIdx.x, lane = t & 63, w = t >> 6;
  int quad = lane >> 4, l16 = lane & 15;
  if (t < 32) {
    pcx[t] = oc[((size_t)n * OPP + pb + t) * 2 + 0] - ocm[n * 2 + 0];
    pcy[t] = oc[((size_t)n * OPP + pb + t) * 2 + 1] - ocm[n * 2 + 1];
  }
  __syncthreads();
  {                                        // layer1: 2 -> 64
    int c = t & 63, pg = t >> 6;
    float wx = w1[c * 2], wy = w1[c * 2 + 1], bb = b1[c];
#pragma unroll
    for (int j = 0; j < 8; ++j) {
      int p = pg * 8 + j;
      act1[p * 72 + c] = (f16)fmaxf(fmaf(wx, pcx[p], fmaf(wy, pcy[p], bb)), 0.0f);
    }
  }
  __syncthreads();
  {                                        // layer2: K=64, N=128; wave n-range 32
    int n0 = w * 32;
    f32x4 acc[2][2] = {};
#pragma unroll
    for (int ks = 0; ks < 2; ++ks) {
      half8 a0 = *(const half8*)(act1 + l16 * 72 + ks * 32 + quad * 8);
      half8 a1 = *(const half8*)(act1 + (16 + l16) * 72 + ks * 32 + quad * 8);
#pragma unroll
      for (int nt = 0; nt < 2; ++nt) {
        half8 bf = *(const half8*)(w2h + (size_t)(n0 + nt * 16 + l16) * 64 + ks * 32 + quad * 8);
        acc[0][nt] = MFMA16(a0, bf, acc[0][nt]);
        acc[1][nt] = MFMA16(a1, bf, acc[1][nt]);
      }
    }
#pragma unroll
    for (int nt = 0; nt < 2; ++nt) {
      int col = n0 + nt * 16 + l16;
      float bb = b2[col];
#pragma unroll
      for (int mt = 0; mt < 2; ++mt)
#pragma unroll
        for (int r = 0; r < 4; ++r)
          act2[(mt * 16 + quad * 4 + r) * 136 + col] = (f16)fmaxf(acc[mt][nt][r] + bb, 0.0f);
    }
  }
  __syncthreads();
  {                                        // layer3: K=128, N=256; wave n-range 64
    int n0 = w * 64;
    f32x4 acc[2][4] = {};
#pragma unroll
    for (int ks = 0; ks < 4; ++ks) {
      half8 a0 = *(const half8*)(act2 + l16 * 136 + ks * 32 + quad * 8);
      half8 a1 = *(const half8*)(act2 + (16 + l16) * 136 + ks * 32 + quad * 8);
#pragma unroll
      for (int nt = 0; nt < 4; ++nt) {
        half8 bf = *(const half8*)(w3h + (size_t)(n0 + nt * 16 + l16) * 128 + ks * 32 + quad * 8);
        acc[0][nt] = MFMA16(a0, bf, acc[0][nt]);
        acc[1][nt] = MFMA16(a1, bf, acc[1][nt]);
      }
    }
#pragma unroll
    for (int nt = 0; nt < 4; ++nt) {
      int col = n0 + nt * 16 + l16;
      float bb = b3[col];
#pragma unroll
      for (int mt = 0; mt < 2; ++mt)
#pragma unroll
        for (int r = 0; r < 4; ++r)
          act3[(mt * 16 + quad * 4 + r) * 264 + col] = (f16)fmaxf(acc[mt][nt][r] + bb, 0.0f);
    }
  }
  __syncthreads();
  {                                        // layer4: K=256, N=512; wave n-range 128; + max
    int n0 = w * 128;
    f32x4 acc[2][8] = {};
#pragma unroll
    for (int ks = 0; ks < 8; ++ks) {
      half8 a0 = *(const half8*)(act3 + l16 * 264 + ks * 32 + quad * 8);
      half8 a1 = *(const half8*)(act3 + (16 + l16) * 264 + ks * 32 + quad * 8);
#pragma unroll
      for (int nt = 0; nt < 8; ++nt) {
        half8 bf = *(const half8*)(w4h + (size_t)(n0 + nt * 16 + l16) * 256 + ks * 32 + quad * 8);
        acc[0][nt] = MFMA16(a0, bf, acc[0][nt]);
        acc[1][nt] = MFMA16(a1, bf, acc[1][nt]);
      }
    }
#pragma unroll
    for (int nt = 0; nt < 8; ++nt) {
      int col = n0 + nt * 16 + l16;
      float bb = b4[col];
      float v = 0.0f;
#pragma unroll
      for (int mt = 0; mt < 2; ++mt)
#pragma unroll
        for (int r = 0; r < 4; ++r)
          v = fmaxf(v, acc[mt][nt][r] + bb);
      v = fmaxf(v, 0.0f);
      v = fmaxf(v, __shfl_xor(v, 16));
      v = fmaxf(v, __shfl_xor(v, 32));
      if (quad == 0)
        atomicMax((int*)obj + (size_t)n * 512 + col, __float_as_int(v));
    }
  }
}

// ======================= classifier layer 1 (1538 -> 1024), MFMA =======================
__global__ __launch_bounds__(256) void cls1_mfma_k(
    const f16* __restrict__ scnh, const float* __restrict__ obj,
    const float* __restrict__ pos, const float* __restrict__ w1raw,
    const f16* __restrict__ w1h, const float* __restrict__ b1,
    f16* __restrict__ h1h) {
  __shared__ f16 act[112 * 72];            // 16128 B
  __shared__ float objl[512];
  __shared__ float odl[128], wAl[128], wBl[128];
  int b = blockIdx.x;                      // 256 = 32 n * 8 octants
  int o8 = b & 7, n = b >> 3;
  int co0 = o8 * 128;
  int t = threadIdx.x, lane = t & 63, w = t >> 6;
  int quad = lane >> 4, l16 = lane & 15;
  objl[t] = obj[(size_t)n * 512 + t];
  objl[t + 256] = obj[(size_t)n * 512 + t + 256];
  __syncthreads();
  if (t < 128) {
    int co = co0 + t;
    const float* wr = w1raw + (size_t)co * 1538;
    float od = 0.0f;
    for (int k = 0; k < 512; ++k) od = fmaf(objl[k], wr[1024 + k], od);
    odl[t] = od + b1[co];
    wAl[t] = wr[1536]; wBl[t] = wr[1537];
  }
  __syncthreads();
  float posx = pos[n * 2 + 0], posy = pos[n * 2 + 1];
  f32x4 acc[7][2];
#pragma unroll
  for (int mt = 0; mt < 7; ++mt)
#pragma unroll
    for (int nt = 0; nt < 2; ++nt) {
      int cl = w * 32 + nt * 16 + l16;
      float od = odl[cl], wA = wAl[cl], wB = wBl[cl];
#pragma unroll
      for (int r = 0; r < 4; ++r) {
        int px = mt * 16 + quad * 4 + r;
        float relx = posx - (-0.5f + ((px / 10) + 0.5f) * 0.1f);
        float rely = posy - (-0.5f + ((px % 10) + 0.5f) * 0.1f);
        acc[mt][nt][r] = od + relx * wA + rely * wB;
      }
    }
  for (int kc = 0; kc < 16; ++kc) {
    int k0 = kc * 64;
    __syncthreads();
    for (int i = t; i < 896; i += 256) {
      int row = i >> 3, c8 = i & 7;
      half8 v = {};
      if (row < 100) v = *(const half8*)(scnh + ((size_t)n * 100 + row) * 1024 + k0 + c8 * 8);
      *(half8*)(act + row * 72 + c8 * 8) = v;
    }
    __syncthreads();
#pragma unroll
    for (int ks = 0; ks < 2; ++ks) {
      half8 bf0 = *(const half8*)(w1h + (size_t)(co0 + w * 32 + l16) * 1024 + k0 + ks * 32 + quad * 8);
      half8 bf1 = *(const half8*)(w1h + (size_t)(co0 + w * 32 + 16 + l16) * 1024 + k0 + ks * 32 + quad * 8);
#pragma unroll
      for (int mt = 0; mt < 7; ++mt) {
        half8 a = *(const half8*)(act + (mt * 16 + l16) * 72 + ks * 32 + quad * 8);
        acc[mt][0] = MFMA16(a, bf0, acc[mt][0]);
        acc[mt][1] = MFMA16(a, bf1, acc[mt][1]);
      }
    }
  }
#pragma unroll
  for (int mt = 0; mt < 7; ++mt)
#pragma unroll
    for (int nt = 0; nt < 2; ++nt) {
      int co = co0 + w * 32 + nt * 16 + l16;
#pragma unroll
      for (int r = 0; r < 4; ++r) {
        int px = mt * 16 + quad * 4 + r;
        if (px < 100)
          h1h[((size_t)n * 100 + px) * 1024 + co] = (f16)fmaxf(acc[mt][nt][r], 0.0f);
      }
    }
}

// ======================= classifier layer 2 (1024 -> 256) =======================
__global__ __launch_bounds__(256) void cls2_k(
    const f16* __restrict__ h1h, const float* __restrict__ w2T,
    const float* __restrict__ b2, float* __restrict__ h2) {
  __shared__ float scT[256 * 28];
  int b = blockIdx.x;
  int q = b & 3, n = b >> 2;
  int t = threadIdx.x, lane = t & 63, w = t >> 6;
  int co = w * 64 + lane;
  int p0 = q * 25;
  float acc[25];
  float bb = b2[co];
#pragma unroll
  for (int j = 0; j < 25; ++j) acc[j] = bb;
  for (int kc = 0; kc < 1024; kc += 256) {
    __syncthreads();
    for (int j = 0; j < 25; ++j)
      scT[t * 28 + j] = (float)h1h[((size_t)n * 100 + p0 + j) * 1024 + kc + t];
    __syncthreads();
    for (int k = 0; k < 256; ++k) {
      float wv = w2T[(size_t)(kc + k) * 256 + co];
      float v[28];
      const float* g = &scT[k * 28];
#pragma unroll
      for (int qq = 0; qq < 7; ++qq) *(float4*)&v[qq * 4] = *(const float4*)&g[qq * 4];
#pragma unroll
      for (int j = 0; j < 25; ++j) acc[j] = fmaf(wv, v[j], acc[j]);
    }
  }
#pragma unroll
  for (int j = 0; j < 25; ++j)
    h2[((size_t)n * 100 + p0 + j) * 256 + co] = fmaxf(acc[j], 0.0f);
}

// ======================= classifier layer 3 (256 -> 1) =======================
__global__ void cls3_k(const float* __restrict__ h2, const float* __restrict__ w3,
                       const float* __restrict__ b3, float* __restrict__ out) {
  int n = blockIdx.x, t = threadIdx.x;
  if (t < 100) {
    float acc = b3[0];
    const float* hp = &h2[((size_t)n * 100 + t) * 256];
    for (int k = 0; k < 256; ++k) acc = fmaf(hp[k], w3[k], acc);
    out[n * 100 + t] = acc;
  }
}

// ======================= launch =======================
extern "C" void kernel_launch(void* const* d_in, const int* in_sizes, int n_in,
                              void* d_out, int out_size, void* d_ws, size_t ws_size,
                              hipStream_t stream) {
  const float* sc      = (const float*)d_in[0];
  const float* oc      = (const float*)d_in[1];
  const float* pos     = (const float*)d_in[2];
  const float* mlp_w1  = (const float*)d_in[3];
  const float* mlp_b1  = (const float*)d_in[4];
  const float* mlp_w2  = (const float*)d_in[5];
  const float* mlp_b2  = (const float*)d_in[6];
  const float* conv1_w = (const float*)d_in[7];
  const float* conv1_b = (const float*)d_in[8];
  const float* conv2_w = (const float*)d_in[9];
  const float* conv2_b = (const float*)d_in[10];
  const float* convt_w = (const float*)d_in[11];
  const float* convt_b = (const float*)d_in[12];
  const float* sa_w1   = (const float*)d_in[13];
  const float* sa_b1   = (const float*)d_in[14];
  const float* sa_w2   = (const float*)d_in[15];
  const float* sa_b2   = (const float*)d_in[16];
  const float* sa_w3   = (const float*)d_in[17];
  const float* sa_b3   = (const float*)d_in[18];
  const float* sa_w4   = (const float*)d_in[19];
  const float* sa_b4   = (const float*)d_in[20];
  const float* cls_w1  = (const float*)d_in[21];
  const float* cls_b1  = (const float*)d_in[22];
  const float* cls_w2  = (const float*)d_in[23];
  const float* cls_b2  = (const float*)d_in[24];
  const float* cls_w3  = (const float*)d_in[25];
  const float* cls_b3  = (const float*)d_in[26];

  float* ws = (float*)d_ws;
  // ---- workspace layout (float units) ----
  f16*   w1h   = (f16*)ws;                         // 589,824 f
  f16*   w2h   = (f16*)(ws + 589824);              // 2,359,296 f (reused: h1h)
  f16*   mw2h  = (f16*)(ws + 2949120);             // 16,384 f
  f16*   saw2h = (f16*)(ws + 2965504);             // 4,096 f
  f16*   saw3h = (f16*)(ws + 2969600);             // 16,384 f
  f16*   saw4h = (f16*)(ws + 2985984);             // 65,536 f
  f16*   cw1h  = (f16*)(ws + 3051520);             // 524,288 f
  f16*   ctwh  = (f16*)(ws + 3575808);             // 1,048,576 f
  float* cw2T  = ws + 4624384;                     // 262,144 f
  float* vox   = ws + 4886528;                     // 3,276,800 f (reused: g1buf, g2buf)
  f16*   voxh  = (f16*)(ws + 8163328);             // 819,200 f (reused: f2h)
  f16*   f1h   = (f16*)(ws + 8982528);             // 819,200 f
  f16*   scnh  = (f16*)(ws + 9801728);             // 1,638,400 f (reused: h2)
  float* obj   = ws + 11440128;                    // 16,384 f
  float* ocm   = ws + 11456512;                    // 64 f

  f16*   g1buf = (f16*)vox;                        // conv1 out (vox dead after cvt16)
  f16*   g2buf = (f16*)vox;                        // conv2 out (g1buf dead after pool1)
  f16*   f2h   = voxh;                             // pool2 out (voxh dead after conv1)
  f16*   h1h   = w2h;                              // cls1 out (w2h dead after conv2)
  float* h2    = (float*)scnh;                     // cls2 out (scnh dead after cls1)
  float* outp  = (float*)d_out;

  // ---- weight preps ----
  wprep_k<512, 256><<<4608, 256, 0, stream>>>(conv1_w, w1h);
  wprep_k<1024, 512><<<18432, 256, 0, stream>>>(conv2_w, w2h);
  cvt16_k<<<32, 256, 0, stream>>>(mlp_w2, mw2h, 8192);
  cvt16_k<<<8, 256, 0, stream>>>(sa_w2, saw2h, 2048);
  cvt16_k<<<32, 256, 0, stream>>>(sa_w3, saw3h, 8192);
  cvt16_k<<<128, 256, 0, stream>>>(sa_w4, saw4h, 32768);
  cw1prep_k<<<4096, 256, 0, stream>>>(cls_w1, cw1h);
  ctprep_k<<<8192, 256, 0, stream>>>(convt_w, ctwh);
  dim3 tb(32, 8);
  transpose_k<<<dim3(32, 8), tb, 0, stream>>>(cls_w2, cw2T, 256, 1024, 1, 0);

  hipMemsetAsync(vox, 0, (size_t)3276800 * 4, stream);
  hipMemsetAsync(obj, 0, (size_t)16384 * 4, stream);
  ocmean_k<<<32, 256, 0, stream>>>(oc, ocm);

  pointnet_mfma_k<<<2048, 256, 0, stream>>>(sc, mlp_w1, mlp_b1, mw2h, mlp_b2, vox);
  cvt16_k<<<3200, 256, 0, stream>>>(vox, voxh, 819200);

  convmfma_k<20, 20, 256, 512, 4><<<512, 256, (7 * 22 + 384) * 80, stream>>>(
      voxh, w1h, conv1_b, g1buf);
  pool1_k<<<3200, 256, 0, stream>>>(g1buf, f1h);
  pack_k<<<800, 256, 0, stream>>>(f1h, scnh);
  convmfma_k<10, 10, 512, 1024, 2><<<512, 256, (7 * 12 + 384) * 80, stream>>>(
      f1h, w2h, conv2_b, g2buf);
  pool2_k<<<1600, 256, 0, stream>>>(g2buf, f2h);
  convt_mfma_k<<<64, 256, 0, stream>>>(f2h, ctwh, convt_b, scnh);

  sa_mfma_k<<<2048, 256, 0, stream>>>(oc, ocm, sa_w1, sa_b1, saw2h, sa_b2,
                                      saw3h, sa_b3, saw4h, sa_b4, obj);

  cls1_mfma_k<<<256, 256, 0, stream>>>(scnh, obj, pos, cls_w1, cw1h, cls_b1, h1h);
  cls2_k<<<128, 256, 0, stream>>>(h1h, cw2T, cls_b2, h2);
  cls3_k<<<32, 128, 0, stream>>>(h2, cls_w3, cls_b3, outp);
}